// Round 1
// baseline (734.115 us; speedup 1.0000x reference)
//
#include <hip/hip_runtime.h>
#include <math.h>

#define B_    8
#define AT_   96
#define NBR_  512
#define NANG_ 125
#define NF_   128
#define NB_   128
#define TN    32
#define TSTRIDE 136   // bf16 elems per row (128 + 8 pad -> 272 B, 16B aligned, conflict-free A-frag reads)
#define YSTRIDE 132   // f32 elems per row (128 + 4 pad)

typedef __attribute__((ext_vector_type(8))) short bf16x8;
typedef __attribute__((ext_vector_type(4))) float f32x4;

__device__ __forceinline__ short f2bf(float f) {
    union { float f; unsigned u; } x; x.f = f;
    unsigned r = x.u + 0x7fffu + ((x.u >> 16) & 1u);
    return (short)(r >> 16);
}

// shifted softplus: softplus(x) - ln2, numerically stable
__device__ __forceinline__ float sspf(float x) {
    return fmaxf(x, 0.f) + log1pf(expf(-fabsf(x))) - 0.69314718055994530942f;
}

// Pack W1 (125x128, zero-pad K to 128) and W2 (128x128) into MFMA B-fragment order:
// wp[((ct*4 + ks)*64 + lane)*8 + j] = W[ks*32 + (lane>>4)*8 + j][ct*16 + (lane&15)]
__global__ void pack_kernel(const float* __restrict__ W1, const float* __restrict__ W2,
                            short* __restrict__ w1p, short* __restrict__ w2p) {
    int idx = blockIdx.x * 256 + threadIdx.x;   // 0..32767
    int t = idx & 16383;
    int j = t & 7, lane = (t >> 3) & 63, ks = (t >> 9) & 3, ct = t >> 11;
    int k = ks * 32 + (lane >> 4) * 8 + j;
    int n = ct * 16 + (lane & 15);
    if (idx < 16384) {
        w1p[t] = (k < NANG_) ? f2bf(W1[k * NF_ + n]) : (short)0;
    } else {
        w2p[t] = f2bf(W2[k * NF_ + n]);
    }
}

// y = x @ Win  -> (768, 128) fp32 in ws
__global__ void in2f_kernel(const float* __restrict__ x, const float* __restrict__ Win,
                            float* __restrict__ y) {
    __shared__ float xs[NB_];
    int row = blockIdx.x;
    int f = threadIdx.x;
    xs[f] = x[row * NB_ + f];
    __syncthreads();
    float acc = 0.f;
    #pragma unroll 8
    for (int k = 0; k < NB_; k++) acc = fmaf(xs[k], Win[k * NF_ + f], acc);
    y[row * NF_ + f] = acc;
}

// One block per (b, atom). Fused: filternet MLP (bf16 MFMA), cfconv elementwise
// gather-multiply, NBR aggregation, f2out + dense + residual.
__global__ __launch_bounds__(256) void triple_kernel(
    const float* __restrict__ x, const float* __restrict__ trip,
    const int* __restrict__ nbj, const int* __restrict__ nbk,
    const float* __restrict__ maskg,
    const float* __restrict__ b1g, const float* __restrict__ b2g,
    const float* __restrict__ Wf2, const float* __restrict__ bf2,
    const float* __restrict__ Wd, const float* __restrict__ bd,
    const float* __restrict__ y, const short* __restrict__ w1p,
    const short* __restrict__ w2p, float* __restrict__ out)
{
    __shared__ short ts[TN * TSTRIDE];   // triple tile, bf16
    __shared__ short hs[TN * TSTRIDE];   // ssp(GEMM1) tile, bf16
    __shared__ float yjs[TN * YSTRIDE];
    __shared__ float yks[TN * YSTRIDE];
    __shared__ float masks[TN];
    __shared__ float aggs[NF_];
    __shared__ float t1s[NF_];

    const int tid  = threadIdx.x;
    const int wave = tid >> 6, lane = tid & 63;
    const int quad = lane >> 4, col = lane & 15;
    const int bid  = blockIdx.x;          // b*96 + a
    const int b    = bid / AT_;

    const long tri_base = (long)bid * NBR_ * NANG_;
    const int  nb_base  = bid * NBR_;

    // wave w owns feature cols [32w, 32w+32): col-tiles ct0, ct1
    const int ct0 = 2 * wave, ct1 = 2 * wave + 1;
    const int f0 = ct0 * 16 + col, f1 = ct1 * 16 + col;
    const float bias1_0 = b1g[f0], bias1_1 = b1g[f1];
    const float bias2_0 = b2g[f0], bias2_1 = b2g[f1];

    float accw0 = 0.f, accw1 = 0.f;

    for (int nt = 0; nt < NBR_ / TN; nt++) {
        __syncthreads();   // protect LDS tiles still being read in previous iter
        // ---- stage triple tile (fp32 -> bf16, K padded to 128) ----
        const float* tp = trip + tri_base + (long)nt * TN * NANG_;
        for (int i = tid; i < TN * 128; i += 256) {
            int r = i >> 7, k = i & 127;
            float v = (k < NANG_) ? tp[r * NANG_ + k] : 0.f;
            ts[r * TSTRIDE + k] = f2bf(v);
        }
        // ---- stage gathered y_j / y_k rows (float4) + mask ----
        for (int i = tid; i < TN * 32; i += 256) {
            int r = i >> 5, c4 = (i & 31) << 2;
            int jj = nbj[nb_base + nt * TN + r];
            int kk = nbk[nb_base + nt * TN + r];
            f32x4 vj = *(const f32x4*)&y[(b * AT_ + jj) * NF_ + c4];
            f32x4 vk = *(const f32x4*)&y[(b * AT_ + kk) * NF_ + c4];
            *(f32x4*)&yjs[r * YSTRIDE + c4] = vj;
            *(f32x4*)&yks[r * YSTRIDE + c4] = vk;
        }
        if (tid < TN) masks[tid] = maskg[nb_base + nt * TN + tid];
        __syncthreads();

        // ---- GEMM1: H = ssp(T @ W1 + b1), 32x128 ----
        f32x4 d00 = {0,0,0,0}, d01 = {0,0,0,0}, d10 = {0,0,0,0}, d11 = {0,0,0,0};
        #pragma unroll
        for (int ks = 0; ks < 4; ks++) {
            bf16x8 a0 = *(const bf16x8*)&ts[(     col) * TSTRIDE + ks * 32 + quad * 8];
            bf16x8 a1 = *(const bf16x8*)&ts[(16 + col) * TSTRIDE + ks * 32 + quad * 8];
            bf16x8 w0 = *(const bf16x8*)&w1p[(ct0 * 4 + ks) * 512 + lane * 8];
            bf16x8 w1 = *(const bf16x8*)&w1p[(ct1 * 4 + ks) * 512 + lane * 8];
            d00 = __builtin_amdgcn_mfma_f32_16x16x32_bf16(a0, w0, d00, 0, 0, 0);
            d01 = __builtin_amdgcn_mfma_f32_16x16x32_bf16(a0, w1, d01, 0, 0, 0);
            d10 = __builtin_amdgcn_mfma_f32_16x16x32_bf16(a1, w0, d10, 0, 0, 0);
            d11 = __builtin_amdgcn_mfma_f32_16x16x32_bf16(a1, w1, d11, 0, 0, 0);
        }
        // C/D layout: col = lane&15, row = quad*4 + reg  [m89-verified]
        #pragma unroll
        for (int r = 0; r < 4; r++) {
            int row0 = quad * 4 + r, row1 = 16 + quad * 4 + r;
            hs[row0 * TSTRIDE + f0] = f2bf(sspf(d00[r] + bias1_0));
            hs[row0 * TSTRIDE + f1] = f2bf(sspf(d01[r] + bias1_1));
            hs[row1 * TSTRIDE + f0] = f2bf(sspf(d10[r] + bias1_0));
            hs[row1 * TSTRIDE + f1] = f2bf(sspf(d11[r] + bias1_1));
        }
        __syncthreads();

        // ---- GEMM2: Wt = H @ W2 + b2, fused conv + aggregate ----
        f32x4 e00 = {0,0,0,0}, e01 = {0,0,0,0}, e10 = {0,0,0,0}, e11 = {0,0,0,0};
        #pragma unroll
        for (int ks = 0; ks < 4; ks++) {
            bf16x8 a0 = *(const bf16x8*)&hs[(     col) * TSTRIDE + ks * 32 + quad * 8];
            bf16x8 a1 = *(const bf16x8*)&hs[(16 + col) * TSTRIDE + ks * 32 + quad * 8];
            bf16x8 w0 = *(const bf16x8*)&w2p[(ct0 * 4 + ks) * 512 + lane * 8];
            bf16x8 w1 = *(const bf16x8*)&w2p[(ct1 * 4 + ks) * 512 + lane * 8];
            e00 = __builtin_amdgcn_mfma_f32_16x16x32_bf16(a0, w0, e00, 0, 0, 0);
            e01 = __builtin_amdgcn_mfma_f32_16x16x32_bf16(a0, w1, e01, 0, 0, 0);
            e10 = __builtin_amdgcn_mfma_f32_16x16x32_bf16(a1, w0, e10, 0, 0, 0);
            e11 = __builtin_amdgcn_mfma_f32_16x16x32_bf16(a1, w1, e11, 0, 0, 0);
        }
        #pragma unroll
        for (int r = 0; r < 4; r++) {
            int row0 = quad * 4 + r, row1 = 16 + quad * 4 + r;
            float m0 = masks[row0], m1 = masks[row1];
            accw0 += (e00[r] + bias2_0) * yjs[row0 * YSTRIDE + f0] * yks[row0 * YSTRIDE + f0] * m0;
            accw1 += (e01[r] + bias2_1) * yjs[row0 * YSTRIDE + f1] * yks[row0 * YSTRIDE + f1] * m0;
            accw0 += (e10[r] + bias2_0) * yjs[row1 * YSTRIDE + f0] * yks[row1 * YSTRIDE + f0] * m1;
            accw1 += (e11[r] + bias2_1) * yjs[row1 * YSTRIDE + f1] * yks[row1 * YSTRIDE + f1] * m1;
        }
    }

    // reduce partial sums across the 4 quads (lanes sharing the same col)
    accw0 += __shfl_xor(accw0, 16, 64);
    accw0 += __shfl_xor(accw0, 32, 64);
    accw1 += __shfl_xor(accw1, 16, 64);
    accw1 += __shfl_xor(accw1, 32, 64);
    if (quad == 0) {
        aggs[ct0 * 16 + col] = accw0;
        aggs[ct1 * 16 + col] = accw1;
    }
    __syncthreads();

    // ---- f2out: v = ssp(agg @ Wf2 + bf2) ----
    if (tid < NF_) {
        float acc = 0.f;
        #pragma unroll 8
        for (int k = 0; k < NF_; k++) acc = fmaf(aggs[k], Wf2[k * NB_ + tid], acc);
        t1s[tid] = sspf(acc + bf2[tid]);
    }
    __syncthreads();
    // ---- dense + residual: out = x + t1 @ Wd + bd ----
    if (tid < NB_) {
        float acc = 0.f;
        #pragma unroll 8
        for (int k = 0; k < NB_; k++) acc = fmaf(t1s[k], Wd[k * NB_ + tid], acc);
        out[bid * NB_ + tid] = x[bid * NB_ + tid] + acc + bd[tid];
    }
}

extern "C" void kernel_launch(void* const* d_in, const int* in_sizes, int n_in,
                              void* d_out, int out_size, void* d_ws, size_t ws_size,
                              hipStream_t stream) {
    const float* x    = (const float*)d_in[0];
    const float* trip = (const float*)d_in[1];
    const int*   nbj  = (const int*)d_in[2];
    const int*   nbk  = (const int*)d_in[3];
    const float* mask = (const float*)d_in[4];
    const float* W1   = (const float*)d_in[5];
    const float* b1   = (const float*)d_in[6];
    const float* W2   = (const float*)d_in[7];
    const float* b2   = (const float*)d_in[8];
    const float* Win  = (const float*)d_in[9];
    const float* Wf2  = (const float*)d_in[10];
    const float* bf2  = (const float*)d_in[11];
    const float* Wd   = (const float*)d_in[12];
    const float* bd   = (const float*)d_in[13];
    float* out = (float*)d_out;

    char* ws = (char*)d_ws;
    float* y   = (float*)ws;                       // 768*128*4 = 393216 B
    short* w1p = (short*)(ws + 393216);            // 32768 B
    short* w2p = (short*)(ws + 393216 + 32768);    // 32768 B

    pack_kernel<<<128, 256, 0, stream>>>(W1, W2, w1p, w2p);
    in2f_kernel<<<B_ * AT_, NF_, 0, stream>>>(x, Win, y);
    triple_kernel<<<B_ * AT_, 256, 0, stream>>>(x, trip, nbj, nbk, mask,
        b1, b2, Wf2, bf2, Wd, bd, y, w1p, w2p, out);
}

// Round 2
// 450.197 us; speedup vs baseline: 1.6307x; 1.6307x over previous
//
#include <hip/hip_runtime.h>
#include <math.h>

#define B_    8
#define AT_   96
#define NBR_  512
#define NANG_ 125
#define NF_   128
#define NB_   128
#define TN    32
#define NCHUNK 4
#define CROWS (NBR_ / NCHUNK)   // 128 neighbors per block
#define TSTRIDE 136             // bf16 elems per row (pad)
#define JSTRIDE 132             // f32 elems per row (pad)

typedef __attribute__((ext_vector_type(8))) short bf16x8;
typedef __attribute__((ext_vector_type(4))) float f32x4;

__device__ __forceinline__ short f2bf(float f) {
    union { float f; unsigned u; } x; x.f = f;
    unsigned r = x.u + 0x7fffu + ((x.u >> 16) & 1u);
    return (short)(r >> 16);
}

__device__ __forceinline__ float sspf(float x) {
    return fmaxf(x, 0.f) + log1pf(expf(-fabsf(x))) - 0.69314718055994530942f;
}

// Fused prep: blocks [0,768) compute y = x@Win (one row each, 128 thr);
// blocks [768,896) pack W1/W2 into MFMA B-fragment order (bf16).
__global__ __launch_bounds__(128) void prep_kernel(
    const float* __restrict__ x, const float* __restrict__ Win,
    const float* __restrict__ W1, const float* __restrict__ W2,
    float* __restrict__ y, short* __restrict__ w1p, short* __restrict__ w2p)
{
    __shared__ float xs[NB_];
    int blk = blockIdx.x, tid = threadIdx.x;
    if (blk < B_ * AT_) {
        xs[tid] = x[blk * NB_ + tid];
        __syncthreads();
        float acc = 0.f;
        #pragma unroll 8
        for (int k = 0; k < NB_; k++) acc = fmaf(xs[k], Win[k * NF_ + tid], acc);
        y[blk * NF_ + tid] = acc;
    } else {
        int t = (blk - B_ * AT_) * 128 + tid;   // [0, 16384)
        int j = t & 7, lane = (t >> 3) & 63, ks = (t >> 9) & 3, ct = t >> 11;
        int k = ks * 32 + (lane >> 4) * 8 + j;
        int n = ct * 16 + (lane & 15);
        w1p[t] = (k < NANG_) ? f2bf(W1[k * NF_ + n]) : (short)0;
        w2p[t] = f2bf(W2[k * NF_ + n]);
    }
}

// One block per (atom, nbr-chunk). Filternet MLP (bf16 MFMA) + conv +
// partial aggregation over 128 neighbors -> pagg.
__global__ __launch_bounds__(256) void triple_partial(
    const float* __restrict__ trip,
    const int* __restrict__ nbj, const int* __restrict__ nbk,
    const float* __restrict__ maskg,
    const float* __restrict__ b1g, const float* __restrict__ b2g,
    const float* __restrict__ y, const short* __restrict__ w1p,
    const short* __restrict__ w2p, float* __restrict__ pagg)
{
    __shared__ short ts[TN * TSTRIDE];
    __shared__ short hs[TN * TSTRIDE];
    __shared__ float yjk[TN * JSTRIDE];

    const int tid = threadIdx.x;
    const int wave = tid >> 6, lane = tid & 63;
    const int quad = lane >> 4, col = lane & 15;
    const int blk = blockIdx.x;            // bid*4 + c
    const int bid = blk >> 2, c = blk & 3;
    const int b = bid / AT_;

    const float* tpc = trip + (long)bid * NBR_ * NANG_ + (long)c * CROWS * NANG_;
    const int nb_base = bid * NBR_ + c * CROWS;

    const int ct0 = 2 * wave, ct1 = 2 * wave + 1;
    const int f0 = ct0 * 16 + col, f1 = ct1 * 16 + col;
    const float bias1_0 = b1g[f0], bias1_1 = b1g[f1];
    const float bias2_0 = b2g[f0], bias2_1 = b2g[f1];

    const int yrow = tid >> 3, ypart = tid & 7;   // yjk staging role

    // zero-pad K columns 125..127 once (never overwritten)
    if (tid < 96) {
        int r = tid / 3, kp = 125 + (tid - 3 * r);
        ts[r * TSTRIDE + kp] = 0;
    }

    float accw0 = 0.f, accw1 = 0.f;

    for (int nt = 0; nt < CROWS / TN; nt++) {
        const float* tp = tpc + nt * TN * NANG_;   // 4000 contiguous floats, 16B aligned
        const int nrow0 = nb_base + nt * TN;

        // ---- issue all global loads for this tile up-front (prefetch) ----
        f32x4 t0 = ((const f32x4*)tp)[tid];
        f32x4 t1 = ((const f32x4*)tp)[tid + 256];
        f32x4 t2 = ((const f32x4*)tp)[tid + 512];
        f32x4 t3 = {0.f, 0.f, 0.f, 0.f};
        if (tid < 232) t3 = ((const f32x4*)tp)[tid + 768];

        const int jj = nbj[nrow0 + yrow], kk = nbk[nrow0 + yrow];
        const float m = maskg[nrow0 + yrow];
        const float* yjp = y + (b * AT_ + jj) * NF_ + ypart * 16;
        const float* ykp = y + (b * AT_ + kk) * NF_ + ypart * 16;
        f32x4 j0 = ((const f32x4*)yjp)[0], j1 = ((const f32x4*)yjp)[1];
        f32x4 j2 = ((const f32x4*)yjp)[2], j3 = ((const f32x4*)yjp)[3];
        f32x4 k0 = ((const f32x4*)ykp)[0], k1 = ((const f32x4*)ykp)[1];
        f32x4 k2 = ((const f32x4*)ykp)[2], k3 = ((const f32x4*)ykp)[3];

        __syncthreads();   // previous iteration's LDS reads complete

        // ---- scatter triple tile to LDS as bf16 ----
        {
            int f = tid * 4, r = f / 125, k = f - r * 125;
            ts[r * TSTRIDE + k] = f2bf(t0.x); if (++k == 125) { k = 0; ++r; }
            ts[r * TSTRIDE + k] = f2bf(t0.y); if (++k == 125) { k = 0; ++r; }
            ts[r * TSTRIDE + k] = f2bf(t0.z); if (++k == 125) { k = 0; ++r; }
            ts[r * TSTRIDE + k] = f2bf(t0.w);
        }
        {
            int f = (tid + 256) * 4, r = f / 125, k = f - r * 125;
            ts[r * TSTRIDE + k] = f2bf(t1.x); if (++k == 125) { k = 0; ++r; }
            ts[r * TSTRIDE + k] = f2bf(t1.y); if (++k == 125) { k = 0; ++r; }
            ts[r * TSTRIDE + k] = f2bf(t1.z); if (++k == 125) { k = 0; ++r; }
            ts[r * TSTRIDE + k] = f2bf(t1.w);
        }
        {
            int f = (tid + 512) * 4, r = f / 125, k = f - r * 125;
            ts[r * TSTRIDE + k] = f2bf(t2.x); if (++k == 125) { k = 0; ++r; }
            ts[r * TSTRIDE + k] = f2bf(t2.y); if (++k == 125) { k = 0; ++r; }
            ts[r * TSTRIDE + k] = f2bf(t2.z); if (++k == 125) { k = 0; ++r; }
            ts[r * TSTRIDE + k] = f2bf(t2.w);
        }
        if (tid < 232) {
            int f = (tid + 768) * 4, r = f / 125, k = f - r * 125;
            ts[r * TSTRIDE + k] = f2bf(t3.x); if (++k == 125) { k = 0; ++r; }
            ts[r * TSTRIDE + k] = f2bf(t3.y); if (++k == 125) { k = 0; ++r; }
            ts[r * TSTRIDE + k] = f2bf(t3.z); if (++k == 125) { k = 0; ++r; }
            ts[r * TSTRIDE + k] = f2bf(t3.w);
        }
        // ---- yjk = y_j * y_k * mask (fp32) ----
        {
            float* d = &yjk[yrow * JSTRIDE + ypart * 16];
            *(f32x4*)(d + 0)  = j0 * k0 * m;
            *(f32x4*)(d + 4)  = j1 * k1 * m;
            *(f32x4*)(d + 8)  = j2 * k2 * m;
            *(f32x4*)(d + 12) = j3 * k3 * m;
        }
        __syncthreads();

        // ---- GEMM1: H = ssp(T @ W1 + b1) ----
        f32x4 d00 = {0,0,0,0}, d01 = {0,0,0,0}, d10 = {0,0,0,0}, d11 = {0,0,0,0};
        #pragma unroll
        for (int ks = 0; ks < 4; ks++) {
            bf16x8 a0 = *(const bf16x8*)&ts[(     col) * TSTRIDE + ks * 32 + quad * 8];
            bf16x8 a1 = *(const bf16x8*)&ts[(16 + col) * TSTRIDE + ks * 32 + quad * 8];
            bf16x8 w0 = *(const bf16x8*)&w1p[(ct0 * 4 + ks) * 512 + lane * 8];
            bf16x8 w1 = *(const bf16x8*)&w1p[(ct1 * 4 + ks) * 512 + lane * 8];
            d00 = __builtin_amdgcn_mfma_f32_16x16x32_bf16(a0, w0, d00, 0, 0, 0);
            d01 = __builtin_amdgcn_mfma_f32_16x16x32_bf16(a0, w1, d01, 0, 0, 0);
            d10 = __builtin_amdgcn_mfma_f32_16x16x32_bf16(a1, w0, d10, 0, 0, 0);
            d11 = __builtin_amdgcn_mfma_f32_16x16x32_bf16(a1, w1, d11, 0, 0, 0);
        }
        #pragma unroll
        for (int r = 0; r < 4; r++) {
            int row0 = quad * 4 + r, row1 = 16 + quad * 4 + r;
            hs[row0 * TSTRIDE + f0] = f2bf(sspf(d00[r] + bias1_0));
            hs[row0 * TSTRIDE + f1] = f2bf(sspf(d01[r] + bias1_1));
            hs[row1 * TSTRIDE + f0] = f2bf(sspf(d10[r] + bias1_0));
            hs[row1 * TSTRIDE + f1] = f2bf(sspf(d11[r] + bias1_1));
        }
        __syncthreads();

        // ---- GEMM2 + fused conv + aggregation ----
        f32x4 e00 = {0,0,0,0}, e01 = {0,0,0,0}, e10 = {0,0,0,0}, e11 = {0,0,0,0};
        #pragma unroll
        for (int ks = 0; ks < 4; ks++) {
            bf16x8 a0 = *(const bf16x8*)&hs[(     col) * TSTRIDE + ks * 32 + quad * 8];
            bf16x8 a1 = *(const bf16x8*)&hs[(16 + col) * TSTRIDE + ks * 32 + quad * 8];
            bf16x8 w0 = *(const bf16x8*)&w2p[(ct0 * 4 + ks) * 512 + lane * 8];
            bf16x8 w1 = *(const bf16x8*)&w2p[(ct1 * 4 + ks) * 512 + lane * 8];
            e00 = __builtin_amdgcn_mfma_f32_16x16x32_bf16(a0, w0, e00, 0, 0, 0);
            e01 = __builtin_amdgcn_mfma_f32_16x16x32_bf16(a0, w1, e01, 0, 0, 0);
            e10 = __builtin_amdgcn_mfma_f32_16x16x32_bf16(a1, w0, e10, 0, 0, 0);
            e11 = __builtin_amdgcn_mfma_f32_16x16x32_bf16(a1, w1, e11, 0, 0, 0);
        }
        #pragma unroll
        for (int r = 0; r < 4; r++) {
            int row0 = quad * 4 + r, row1 = 16 + quad * 4 + r;
            accw0 += (e00[r] + bias2_0) * yjk[row0 * JSTRIDE + f0];
            accw1 += (e01[r] + bias2_1) * yjk[row0 * JSTRIDE + f1];
            accw0 += (e10[r] + bias2_0) * yjk[row1 * JSTRIDE + f0];
            accw1 += (e11[r] + bias2_1) * yjk[row1 * JSTRIDE + f1];
        }
    }

    // reduce partials across quads; write per-chunk partial aggregate
    accw0 += __shfl_xor(accw0, 16, 64);
    accw0 += __shfl_xor(accw0, 32, 64);
    accw1 += __shfl_xor(accw1, 16, 64);
    accw1 += __shfl_xor(accw1, 32, 64);
    if (quad == 0) {
        pagg[blk * NF_ + f0] = accw0;
        pagg[blk * NF_ + f1] = accw1;
    }
}

// Sum 4 partials, f2out (ssp), dense, residual.
__global__ __launch_bounds__(128) void finish_kernel(
    const float* __restrict__ x, const float* __restrict__ pagg,
    const float* __restrict__ Wf2, const float* __restrict__ bf2,
    const float* __restrict__ Wd, const float* __restrict__ bd,
    float* __restrict__ out)
{
    __shared__ float aggs[NF_];
    __shared__ float t1s[NF_];
    int bid = blockIdx.x, f = threadIdx.x;
    float a = pagg[(bid * 4 + 0) * NF_ + f] + pagg[(bid * 4 + 1) * NF_ + f]
            + pagg[(bid * 4 + 2) * NF_ + f] + pagg[(bid * 4 + 3) * NF_ + f];
    aggs[f] = a;
    __syncthreads();
    float acc = 0.f;
    #pragma unroll 8
    for (int k = 0; k < NF_; k++) acc = fmaf(aggs[k], Wf2[k * NB_ + f], acc);
    t1s[f] = sspf(acc + bf2[f]);
    __syncthreads();
    acc = 0.f;
    #pragma unroll 8
    for (int k = 0; k < NB_; k++) acc = fmaf(t1s[k], Wd[k * NB_ + f], acc);
    out[bid * NB_ + f] = x[bid * NB_ + f] + acc + bd[f];
}

extern "C" void kernel_launch(void* const* d_in, const int* in_sizes, int n_in,
                              void* d_out, int out_size, void* d_ws, size_t ws_size,
                              hipStream_t stream) {
    const float* x    = (const float*)d_in[0];
    const float* trip = (const float*)d_in[1];
    const int*   nbj  = (const int*)d_in[2];
    const int*   nbk  = (const int*)d_in[3];
    const float* mask = (const float*)d_in[4];
    const float* W1   = (const float*)d_in[5];
    const float* b1   = (const float*)d_in[6];
    const float* W2   = (const float*)d_in[7];
    const float* b2   = (const float*)d_in[8];
    const float* Win  = (const float*)d_in[9];
    const float* Wf2  = (const float*)d_in[10];
    const float* bf2  = (const float*)d_in[11];
    const float* Wd   = (const float*)d_in[12];
    const float* bd   = (const float*)d_in[13];
    float* out = (float*)d_out;

    char* ws = (char*)d_ws;
    float* y    = (float*)ws;                        // 393216 B
    short* w1p  = (short*)(ws + 393216);             // 32768 B
    short* w2p  = (short*)(ws + 393216 + 32768);     // 32768 B
    float* pagg = (float*)(ws + 393216 + 65536);     // 3072*128*4 = 1572864 B

    prep_kernel<<<B_ * AT_ + 128, 128, 0, stream>>>(x, Win, W1, W2, y, w1p, w2p);
    triple_partial<<<B_ * AT_ * NCHUNK, 256, 0, stream>>>(trip, nbj, nbk, mask,
        b1, b2, y, w1p, w2p, pagg);
    finish_kernel<<<B_ * AT_, 128, 0, stream>>>(x, pagg, Wf2, bf2, Wd, bd, out);
}

// Round 3
// 346.297 us; speedup vs baseline: 2.1199x; 1.3000x over previous
//
#include <hip/hip_runtime.h>
#include <math.h>

#define B_    8
#define AT_   96
#define NBR_  512
#define NANG_ 125
#define NF_   128
#define NB_   128
#define TN    32
#define NCHUNK 4
#define CROWS (NBR_ / NCHUNK)   // 128 neighbors per block
#define TSTRIDE 136             // bf16 elems per row (pad)
#define JSTRIDE 132             // f32 elems per row (pad)

typedef __attribute__((ext_vector_type(8))) short bf16x8;
typedef __attribute__((ext_vector_type(4))) float f32x4;

// cheap bf16 convert: round-half-up, 2 VALU ops
__device__ __forceinline__ short f2bf(float f) {
    union { float f; unsigned u; } x; x.f = f;
    return (short)((x.u + 0x8000u) >> 16);
}

// shifted softplus on HW transcendentals:
// ssp(x) = ln2 * (log2(1 + exp2(x*log2e)) - 1)
// exact limits: x->-inf => -ln2 ; large x => x - ln2. ~5 VALU ops.
__device__ __forceinline__ float sspf(float x) {
    float p = __builtin_amdgcn_exp2f(x * 1.44269504088896340736f);
    float l = __builtin_amdgcn_logf(1.0f + p);     // v_log_f32 = log2
    return 0.69314718055994530942f * l - 0.69314718055994530942f;
}

// Fused prep: blocks [0,192) compute y = x@Win for 4 rows each;
// blocks [192,320) pack W1/W2 into MFMA B-fragment order (bf16).
__global__ __launch_bounds__(128) void prep_kernel(
    const float* __restrict__ x, const float* __restrict__ Win,
    const float* __restrict__ W1, const float* __restrict__ W2,
    float* __restrict__ y, short* __restrict__ w1p, short* __restrict__ w2p)
{
    __shared__ float xs[4][NB_];
    int blk = blockIdx.x, tid = threadIdx.x;
    if (blk < 192) {
        int row0 = blk * 4;
        #pragma unroll
        for (int r = 0; r < 4; r++) xs[r][tid] = x[(row0 + r) * NB_ + tid];
        __syncthreads();
        float a0 = 0.f, a1 = 0.f, a2 = 0.f, a3 = 0.f;
        #pragma unroll 8
        for (int k = 0; k < NB_; k++) {
            float w = Win[k * NF_ + tid];
            a0 = fmaf(xs[0][k], w, a0);
            a1 = fmaf(xs[1][k], w, a1);
            a2 = fmaf(xs[2][k], w, a2);
            a3 = fmaf(xs[3][k], w, a3);
        }
        y[(row0 + 0) * NF_ + tid] = a0;
        y[(row0 + 1) * NF_ + tid] = a1;
        y[(row0 + 2) * NF_ + tid] = a2;
        y[(row0 + 3) * NF_ + tid] = a3;
    } else {
        int t = (blk - 192) * 128 + tid;   // [0, 16384)
        int j = t & 7, lane = (t >> 3) & 63, ks = (t >> 9) & 3, ct = t >> 11;
        int k = ks * 32 + (lane >> 4) * 8 + j;
        int n = ct * 16 + (lane & 15);
        w1p[t] = (k < NANG_) ? f2bf(W1[k * NF_ + n]) : (short)0;
        w2p[t] = f2bf(W2[k * NF_ + n]);
    }
}

// One block per (atom, nbr-chunk). Filternet MLP (bf16 MFMA) + conv +
// partial aggregation over 128 neighbors -> pagg.
__global__ __launch_bounds__(256) void triple_partial(
    const float* __restrict__ trip,
    const int* __restrict__ nbj, const int* __restrict__ nbk,
    const float* __restrict__ maskg,
    const float* __restrict__ b1g, const float* __restrict__ b2g,
    const float* __restrict__ y, const short* __restrict__ w1p,
    const short* __restrict__ w2p, float* __restrict__ pagg)
{
    __shared__ short ts[TN * TSTRIDE];
    __shared__ short hs[TN * TSTRIDE];
    __shared__ float yjk[TN * JSTRIDE];

    const int tid = threadIdx.x;
    const int wave = tid >> 6, lane = tid & 63;
    const int quad = lane >> 4, col = lane & 15;
    const int blk = blockIdx.x;            // bid*4 + c
    const int bid = blk >> 2, c = blk & 3;
    const int b = bid / AT_;

    const float* tpc = trip + (long)bid * NBR_ * NANG_ + (long)c * CROWS * NANG_;
    const int nb_base = bid * NBR_ + c * CROWS;

    const int ct0 = 2 * wave, ct1 = 2 * wave + 1;
    const int f0 = ct0 * 16 + col, f1 = ct1 * 16 + col;
    const float bias1_0 = b1g[f0], bias1_1 = b1g[f1];
    const float bias2_0 = b2g[f0], bias2_1 = b2g[f1];

    const int yrow = tid >> 3, ypart = tid & 7;   // yjk staging role

    // zero-pad K columns 125..127 once (never overwritten)
    if (tid < 96) {
        int r = tid / 3, kp = 125 + (tid - 3 * r);
        ts[r * TSTRIDE + kp] = 0;
    }

    float accw0 = 0.f, accw1 = 0.f;

    for (int nt = 0; nt < CROWS / TN; nt++) {
        const float* tp = tpc + nt * TN * NANG_;   // 4000 contiguous floats, 16B aligned
        const int nrow0 = nb_base + nt * TN;

        // ---- issue all global loads for this tile up-front (prefetch) ----
        f32x4 t0 = ((const f32x4*)tp)[tid];
        f32x4 t1 = ((const f32x4*)tp)[tid + 256];
        f32x4 t2 = ((const f32x4*)tp)[tid + 512];
        f32x4 t3 = {0.f, 0.f, 0.f, 0.f};
        if (tid < 232) t3 = ((const f32x4*)tp)[tid + 768];

        const int jj = nbj[nrow0 + yrow], kk = nbk[nrow0 + yrow];
        const float m = maskg[nrow0 + yrow];
        const float* yjp = y + (b * AT_ + jj) * NF_ + ypart * 16;
        const float* ykp = y + (b * AT_ + kk) * NF_ + ypart * 16;
        f32x4 j0 = ((const f32x4*)yjp)[0], j1 = ((const f32x4*)yjp)[1];
        f32x4 j2 = ((const f32x4*)yjp)[2], j3 = ((const f32x4*)yjp)[3];
        f32x4 k0 = ((const f32x4*)ykp)[0], k1 = ((const f32x4*)ykp)[1];
        f32x4 k2 = ((const f32x4*)ykp)[2], k3 = ((const f32x4*)ykp)[3];

        __syncthreads();   // previous iteration's LDS reads complete

        // ---- scatter triple tile to LDS as bf16 ----
        {
            int f = tid * 4, r = f / 125, k = f - r * 125;
            ts[r * TSTRIDE + k] = f2bf(t0.x); if (++k == 125) { k = 0; ++r; }
            ts[r * TSTRIDE + k] = f2bf(t0.y); if (++k == 125) { k = 0; ++r; }
            ts[r * TSTRIDE + k] = f2bf(t0.z); if (++k == 125) { k = 0; ++r; }
            ts[r * TSTRIDE + k] = f2bf(t0.w);
        }
        {
            int f = (tid + 256) * 4, r = f / 125, k = f - r * 125;
            ts[r * TSTRIDE + k] = f2bf(t1.x); if (++k == 125) { k = 0; ++r; }
            ts[r * TSTRIDE + k] = f2bf(t1.y); if (++k == 125) { k = 0; ++r; }
            ts[r * TSTRIDE + k] = f2bf(t1.z); if (++k == 125) { k = 0; ++r; }
            ts[r * TSTRIDE + k] = f2bf(t1.w);
        }
        {
            int f = (tid + 512) * 4, r = f / 125, k = f - r * 125;
            ts[r * TSTRIDE + k] = f2bf(t2.x); if (++k == 125) { k = 0; ++r; }
            ts[r * TSTRIDE + k] = f2bf(t2.y); if (++k == 125) { k = 0; ++r; }
            ts[r * TSTRIDE + k] = f2bf(t2.z); if (++k == 125) { k = 0; ++r; }
            ts[r * TSTRIDE + k] = f2bf(t2.w);
        }
        if (tid < 232) {
            int f = (tid + 768) * 4, r = f / 125, k = f - r * 125;
            ts[r * TSTRIDE + k] = f2bf(t3.x); if (++k == 125) { k = 0; ++r; }
            ts[r * TSTRIDE + k] = f2bf(t3.y); if (++k == 125) { k = 0; ++r; }
            ts[r * TSTRIDE + k] = f2bf(t3.z); if (++k == 125) { k = 0; ++r; }
            ts[r * TSTRIDE + k] = f2bf(t3.w);
        }
        // ---- yjk = y_j * y_k * mask (fp32) ----
        {
            float* d = &yjk[yrow * JSTRIDE + ypart * 16];
            *(f32x4*)(d + 0)  = j0 * k0 * m;
            *(f32x4*)(d + 4)  = j1 * k1 * m;
            *(f32x4*)(d + 8)  = j2 * k2 * m;
            *(f32x4*)(d + 12) = j3 * k3 * m;
        }
        __syncthreads();

        // ---- GEMM1: H = ssp(T @ W1 + b1) ----
        f32x4 d00 = {0,0,0,0}, d01 = {0,0,0,0}, d10 = {0,0,0,0}, d11 = {0,0,0,0};
        #pragma unroll
        for (int ks = 0; ks < 4; ks++) {
            bf16x8 a0 = *(const bf16x8*)&ts[(     col) * TSTRIDE + ks * 32 + quad * 8];
            bf16x8 a1 = *(const bf16x8*)&ts[(16 + col) * TSTRIDE + ks * 32 + quad * 8];
            bf16x8 w0 = *(const bf16x8*)&w1p[(ct0 * 4 + ks) * 512 + lane * 8];
            bf16x8 w1 = *(const bf16x8*)&w1p[(ct1 * 4 + ks) * 512 + lane * 8];
            d00 = __builtin_amdgcn_mfma_f32_16x16x32_bf16(a0, w0, d00, 0, 0, 0);
            d01 = __builtin_amdgcn_mfma_f32_16x16x32_bf16(a0, w1, d01, 0, 0, 0);
            d10 = __builtin_amdgcn_mfma_f32_16x16x32_bf16(a1, w0, d10, 0, 0, 0);
            d11 = __builtin_amdgcn_mfma_f32_16x16x32_bf16(a1, w1, d11, 0, 0, 0);
        }
        #pragma unroll
        for (int r = 0; r < 4; r++) {
            int row0 = quad * 4 + r, row1 = 16 + quad * 4 + r;
            hs[row0 * TSTRIDE + f0] = f2bf(sspf(d00[r] + bias1_0));
            hs[row0 * TSTRIDE + f1] = f2bf(sspf(d01[r] + bias1_1));
            hs[row1 * TSTRIDE + f0] = f2bf(sspf(d10[r] + bias1_0));
            hs[row1 * TSTRIDE + f1] = f2bf(sspf(d11[r] + bias1_1));
        }
        __syncthreads();

        // ---- GEMM2 + fused conv + aggregation ----
        f32x4 e00 = {0,0,0,0}, e01 = {0,0,0,0}, e10 = {0,0,0,0}, e11 = {0,0,0,0};
        #pragma unroll
        for (int ks = 0; ks < 4; ks++) {
            bf16x8 a0 = *(const bf16x8*)&hs[(     col) * TSTRIDE + ks * 32 + quad * 8];
            bf16x8 a1 = *(const bf16x8*)&hs[(16 + col) * TSTRIDE + ks * 32 + quad * 8];
            bf16x8 w0 = *(const bf16x8*)&w2p[(ct0 * 4 + ks) * 512 + lane * 8];
            bf16x8 w1 = *(const bf16x8*)&w2p[(ct1 * 4 + ks) * 512 + lane * 8];
            e00 = __builtin_amdgcn_mfma_f32_16x16x32_bf16(a0, w0, e00, 0, 0, 0);
            e01 = __builtin_amdgcn_mfma_f32_16x16x32_bf16(a0, w1, e01, 0, 0, 0);
            e10 = __builtin_amdgcn_mfma_f32_16x16x32_bf16(a1, w0, e10, 0, 0, 0);
            e11 = __builtin_amdgcn_mfma_f32_16x16x32_bf16(a1, w1, e11, 0, 0, 0);
        }
        #pragma unroll
        for (int r = 0; r < 4; r++) {
            int row0 = quad * 4 + r, row1 = 16 + quad * 4 + r;
            accw0 += (e00[r] + bias2_0) * yjk[row0 * JSTRIDE + f0];
            accw1 += (e01[r] + bias2_1) * yjk[row0 * JSTRIDE + f1];
            accw0 += (e10[r] + bias2_0) * yjk[row1 * JSTRIDE + f0];
            accw1 += (e11[r] + bias2_1) * yjk[row1 * JSTRIDE + f1];
        }
    }

    // reduce partials across quads; write per-chunk partial aggregate
    accw0 += __shfl_xor(accw0, 16, 64);
    accw0 += __shfl_xor(accw0, 32, 64);
    accw1 += __shfl_xor(accw1, 16, 64);
    accw1 += __shfl_xor(accw1, 32, 64);
    if (quad == 0) {
        pagg[blk * NF_ + f0] = accw0;
        pagg[blk * NF_ + f1] = accw1;
    }
}

// Sum 4 partials, f2out (ssp), dense, residual.
__global__ __launch_bounds__(128) void finish_kernel(
    const float* __restrict__ x, const float* __restrict__ pagg,
    const float* __restrict__ Wf2, const float* __restrict__ bf2,
    const float* __restrict__ Wd, const float* __restrict__ bd,
    float* __restrict__ out)
{
    __shared__ float aggs[NF_];
    __shared__ float t1s[NF_];
    int bid = blockIdx.x, f = threadIdx.x;
    float a = pagg[(bid * 4 + 0) * NF_ + f] + pagg[(bid * 4 + 1) * NF_ + f]
            + pagg[(bid * 4 + 2) * NF_ + f] + pagg[(bid * 4 + 3) * NF_ + f];
    aggs[f] = a;
    __syncthreads();
    float acc = 0.f;
    #pragma unroll 8
    for (int k = 0; k < NF_; k++) acc = fmaf(aggs[k], Wf2[k * NB_ + f], acc);
    t1s[f] = sspf(acc + bf2[f]);
    __syncthreads();
    acc = 0.f;
    #pragma unroll 8
    for (int k = 0; k < NB_; k++) acc = fmaf(t1s[k], Wd[k * NB_ + f], acc);
    out[bid * NB_ + f] = x[bid * NB_ + f] + acc + bd[f];
}

extern "C" void kernel_launch(void* const* d_in, const int* in_sizes, int n_in,
                              void* d_out, int out_size, void* d_ws, size_t ws_size,
                              hipStream_t stream) {
    const float* x    = (const float*)d_in[0];
    const float* trip = (const float*)d_in[1];
    const int*   nbj  = (const int*)d_in[2];
    const int*   nbk  = (const int*)d_in[3];
    const float* mask = (const float*)d_in[4];
    const float* W1   = (const float*)d_in[5];
    const float* b1   = (const float*)d_in[6];
    const float* W2   = (const float*)d_in[7];
    const float* b2   = (const float*)d_in[8];
    const float* Win  = (const float*)d_in[9];
    const float* Wf2  = (const float*)d_in[10];
    const float* bf2  = (const float*)d_in[11];
    const float* Wd   = (const float*)d_in[12];
    const float* bd   = (const float*)d_in[13];
    float* out = (float*)d_out;

    char* ws = (char*)d_ws;
    float* y    = (float*)ws;                        // 393216 B
    short* w1p  = (short*)(ws + 393216);             // 32768 B
    short* w2p  = (short*)(ws + 393216 + 32768);     // 32768 B
    float* pagg = (float*)(ws + 393216 + 65536);     // 3072*128*4 = 1572864 B

    prep_kernel<<<320, 128, 0, stream>>>(x, Win, W1, W2, y, w1p, w2p);
    triple_partial<<<B_ * AT_ * NCHUNK, 256, 0, stream>>>(trip, nbj, nbk, mask,
        b1, b2, y, w1p, w2p, pagg);
    finish_kernel<<<B_ * AT_, 128, 0, stream>>>(x, pagg, Wf2, bf2, Wd, bd, out);
}